// Round 5
// baseline (832.713 us; speedup 1.0000x reference)
//
#include <hip/hip_runtime.h>

typedef unsigned short u16;
typedef __bf16  bf16x8 __attribute__((ext_vector_type(8)));
typedef float   f32x4  __attribute__((ext_vector_type(4)));

#define N_ROWS 1500000
#define S_SEG  16384
#define ROWS_PB 64

__device__ __forceinline__ u16 f2bf(float f) {
    unsigned int u = __float_as_uint(f);
    u += 0x7FFF + ((u >> 16) & 1);   // RNE
    return (u16)(u >> 16);
}

// ---------------- zero the fp32 segment accumulators ----------------
__global__ void zero_ws_kernel(float* p, int n4) {
    int i = blockIdx.x * 256 + threadIdx.x;
    if (i < n4) reinterpret_cast<float4*>(p)[i] = make_float4(0.f, 0.f, 0.f, 0.f);
}

// ------- transpose + fp32->bf16 convert the 4 big-GEMM weight matrices -------
// W0 [64,128] fp32 -> W0T [128][64] bf16;  W1 [128,32] -> W1T [32][128]; same for rl.
__global__ void transpose_weights(const float* __restrict__ w0, const float* __restrict__ w1,
                                  const float* __restrict__ r0, const float* __restrict__ r1,
                                  u16* __restrict__ w0T, u16* __restrict__ w1T,
                                  u16* __restrict__ r0T, u16* __restrict__ r1T) {
    int idx = blockIdx.x * 256 + threadIdx.x;     // 0 .. 24576
    if (idx < 8192) {
        int o = idx >> 6, k = idx & 63;
        w0T[o * 64 + k] = f2bf(w0[k * 128 + o]);
    } else if (idx < 12288) {
        int t = idx - 8192; int o = t >> 7, k = t & 127;
        w1T[o * 128 + k] = f2bf(w1[k * 32 + o]);
    } else if (idx < 20480) {
        int t = idx - 12288; int o = t >> 6, k = t & 63;
        r0T[o * 64 + k] = f2bf(r0[k * 128 + o]);
    } else if (idx < 24576) {
        int t = idx - 20480; int o = t >> 7, k = t & 127;
        r1T[o * 128 + k] = f2bf(r1[k * 32 + o]);
    }
}

// ---------------- main: per-row 2-layer MLP x2 branches + segment atomics ----------------
// 64 rows/block, 4 waves, MFMA 16x16x32 bf16.
// A-frag: A[m=lane&15][k=(lane>>4)*8+j];  B-frag: B[k=(lane>>4)*8+j][n=lane&15]
// C/D   : col=lane&15, row=(lane>>4)*4+reg
// LDS: 9216 + 17408 + 8448 + 256 = 35328 B -> 4 blocks/CU.
#define XS_LD 72
#define H1_LD 136
#define H2_LD 33

__global__ __launch_bounds__(256) void main_mlp_seg(
    const float* __restrict__ x, const int* __restrict__ seg_ids,
    const u16* __restrict__ w0T, const float* __restrict__ b0a,
    const u16* __restrict__ w1T, const float* __restrict__ b1a,
    const u16* __restrict__ r0T, const float* __restrict__ rb0,
    const u16* __restrict__ r1T, const float* __restrict__ rb1,
    float* __restrict__ seg_out, float* __restrict__ rseg_out)
{
    __shared__ u16   xs [ROWS_PB * XS_LD];
    __shared__ u16   h1s[ROWS_PB * H1_LD];
    __shared__ float h2s[ROWS_PB * H2_LD];
    __shared__ int   s_ids[ROWS_PB];

    const int tid = threadIdx.x;
    const int i0  = blockIdx.x * ROWS_PB;

    if (tid < ROWS_PB) {
        int row = i0 + tid;
        s_ids[tid] = (row < N_ROWS) ? seg_ids[row] : -1;
    }
    // stage x tile: 64 rows x 64 fp32, convert -> bf16 in LDS (coalesced float4).
    #pragma unroll
    for (int j = 0; j < 4; ++j) {
        int ch = tid + j * 256;          // 0..1023
        int r = ch >> 4, c4 = ch & 15;   // 16 float4 per row
        int row = i0 + r;
        float4 v = make_float4(0.f, 0.f, 0.f, 0.f);
        if (row < N_ROWS) v = *reinterpret_cast<const float4*>(x + (size_t)row * 64 + c4 * 4);
        ushort4 pk;
        pk.x = f2bf(v.x); pk.y = f2bf(v.y); pk.z = f2bf(v.z); pk.w = f2bf(v.w);
        *reinterpret_cast<ushort4*>(&xs[r * XS_LD + c4 * 4]) = pk;
    }
    __syncthreads();

    const int wid = tid >> 6, lane = tid & 63;
    const int m = lane & 15, q = lane >> 4;

    #pragma unroll 1
    for (int br = 0; br < 2; ++br) {
        const u16*   W0 = br ? r0T : w0T;
        const float* B0 = br ? rb0 : b0a;
        const u16*   W1 = br ? r1T : w1T;
        const float* B1 = br ? rb1 : b1a;
        float* segp = br ? rseg_out : seg_out;

        // ---- GEMM1: [64,64] @ [64,128] -> relu -> h1s (bf16) ----
        // wave `wid` owns col-tiles {2*wid, 2*wid+1}, loops 4 row-tiles
        bf16x8 bf[2][2];
        float bias0v[2];
        #pragma unroll
        for (int ct = 0; ct < 2; ++ct) {
            int n0 = (2 * wid + ct) * 16;
            #pragma unroll
            for (int ks = 0; ks < 2; ++ks)
                bf[ct][ks] = *reinterpret_cast<const bf16x8*>(W0 + (n0 + m) * 64 + ks * 32 + q * 8);
            bias0v[ct] = B0[n0 + m];
        }
        #pragma unroll
        for (int rt = 0; rt < 4; ++rt) {
            bf16x8 a0 = *reinterpret_cast<const bf16x8*>(&xs[(rt * 16 + m) * XS_LD + 0  + q * 8]);
            bf16x8 a1 = *reinterpret_cast<const bf16x8*>(&xs[(rt * 16 + m) * XS_LD + 32 + q * 8]);
            #pragma unroll
            for (int ct = 0; ct < 2; ++ct) {
                f32x4 acc = {0.f, 0.f, 0.f, 0.f};
                acc = __builtin_amdgcn_mfma_f32_16x16x32_bf16(a0, bf[ct][0], acc, 0, 0, 0);
                acc = __builtin_amdgcn_mfma_f32_16x16x32_bf16(a1, bf[ct][1], acc, 0, 0, 0);
                int colg = (2 * wid + ct) * 16 + m;
                #pragma unroll
                for (int i = 0; i < 4; ++i) {
                    float v = fmaxf(acc[i] + bias0v[ct], 0.f);
                    h1s[(rt * 16 + q * 4 + i) * H1_LD + colg] = f2bf(v);
                }
            }
        }
        __syncthreads();

        // ---- GEMM2: [64,128] @ [128,32] -> relu -> h2s (fp32) ----
        // wave `wid` owns row-tile wid, both col-tiles
        bf16x8 bg[2][4];
        float bias1v[2];
        #pragma unroll
        for (int ct = 0; ct < 2; ++ct) {
            int n0 = ct * 16;
            #pragma unroll
            for (int ks = 0; ks < 4; ++ks)
                bg[ct][ks] = *reinterpret_cast<const bf16x8*>(W1 + (n0 + m) * 128 + ks * 32 + q * 8);
            bias1v[ct] = B1[n0 + m];
        }
        {
            int rt = wid;
            bf16x8 a[4];
            #pragma unroll
            for (int ks = 0; ks < 4; ++ks)
                a[ks] = *reinterpret_cast<const bf16x8*>(&h1s[(rt * 16 + m) * H1_LD + ks * 32 + q * 8]);
            #pragma unroll
            for (int ct = 0; ct < 2; ++ct) {
                f32x4 acc = {0.f, 0.f, 0.f, 0.f};
                #pragma unroll
                for (int ks = 0; ks < 4; ++ks)
                    acc = __builtin_amdgcn_mfma_f32_16x16x32_bf16(a[ks], bg[ct][ks], acc, 0, 0, 0);
                int colg = ct * 16 + m;
                #pragma unroll
                for (int i = 0; i < 4; ++i) {
                    float v = fmaxf(acc[i] + bias1v[ct], 0.f);
                    h2s[(rt * 16 + q * 4 + i) * H2_LD + colg] = v;
                }
            }
        }
        __syncthreads();

        // ---- sorted-run segment accumulate: thread = (col, 8-row group) ----
        {
            int c = tid & 31, g = tid >> 5;      // 8 groups x 8 rows
            int cur = -1; float acc = 0.f;
            #pragma unroll
            for (int r = 0; r < 8; ++r) {
                int rr = g * 8 + r;
                int id = s_ids[rr];
                if (id != cur) {
                    if (cur >= 0) atomicAdd(&segp[cur * 32 + c], acc);
                    cur = id; acc = 0.f;
                }
                if (cur >= 0) acc += h2s[rr * H2_LD + c];
            }
            if (cur >= 0) atomicAdd(&segp[cur * 32 + c], acc);
        }
        // safe without extra barrier: next-branch GEMM1 writes h1s (last read
        // before the prior barrier); h2s rewritten only after that barrier.
    }
}

// ---------------- per-segment heads + cost MLP + policy (fp32 in, fp32 out) ----------------
__global__ __launch_bounds__(256) void heads_kernel(
    const float* __restrict__ seg, const float* __restrict__ rseg,
    const float* __restrict__ fwd0_w, const float* __restrict__ fwd0_b,
    const float* __restrict__ fwd1_w, const float* __restrict__ fwd1_b,
    const float* __restrict__ com0_w, const float* __restrict__ com0_b,
    const float* __restrict__ com1_w, const float* __restrict__ com1_b,
    const float* __restrict__ bwd0_w, const float* __restrict__ bwd0_b,
    const float* __restrict__ bwd1_w, const float* __restrict__ bwd1_b,
    const float* __restrict__ cost0_w, const float* __restrict__ cost0_b,
    const float* __restrict__ cost1_w, const float* __restrict__ cost1_b,
    const float* __restrict__ pol_w, const float* __restrict__ pol_b,
    float* __restrict__ out)
{
    __shared__ float s_seg[4][32];
    __shared__ float s_rseg[4][32];
    __shared__ float s_c0[4][64];
    const int tid = threadIdx.x, wid = tid >> 6, lane = tid & 63;
    const int s = blockIdx.x * 4 + wid;

    if (lane < 32) {
        s_seg[wid][lane]  = seg[s * 32 + lane];
        s_rseg[wid][lane] = rseg[s * 32 + lane];
    }
    __syncthreads();

    const float* w0s[3] = {fwd0_w, com0_w, bwd0_w};
    const float* b0s[3] = {fwd0_b, com0_b, bwd0_b};
    const float* w1s[3] = {fwd1_w, com1_w, bwd1_w};
    const float* b1s[3] = {fwd1_b, com1_b, bwd1_b};
    float costs[3];
    #pragma unroll
    for (int hh = 0; hh < 3; ++hh) {
        float t = 0.f;
        #pragma unroll
        for (int k = 0; k < 32; ++k)
            t = fmaf(s_seg[wid][k], w0s[hh][k * 64 + lane], t);
        t = fmaxf(t + b0s[hh][lane], 0.f);
        float red = t * w1s[hh][lane];
        red += __shfl_down(red, 32);
        red += __shfl_down(red, 16);
        red += __shfl_down(red, 8);
        red += __shfl_down(red, 4);
        red += __shfl_down(red, 2);
        red += __shfl_down(red, 1);
        costs[hh] = __shfl(red, 0) + b1s[hh][0];
    }

    // cost MLP layer 0: 3 -> 64 (lane j owns output j)
    float c0 = costs[0] * cost0_w[lane] +
               costs[1] * cost0_w[64 + lane] +
               costs[2] * cost0_w[128 + lane] + cost0_b[lane];
    c0 = fmaxf(c0, 0.f);
    s_c0[wid][lane] = c0;
    __syncthreads();

    // layer 1: 64 -> 32 (lanes duplicate over kk = lane&31)
    int kk = lane & 31;
    float c1 = 0.f;
    #pragma unroll 8
    for (int j = 0; j < 64; ++j)
        c1 = fmaf(s_c0[wid][j], cost1_w[j * 32 + kk], c1);
    c1 = fmaxf(c1 + cost1_b[kk], 0.f);

    // policy: latent = [rseg(32), c(32)] . pol_w
    float p = 0.f;
    if (lane < 32)
        p = s_rseg[wid][lane] * pol_w[lane] + c1 * pol_w[32 + lane];
    p += __shfl_down(p, 32);
    p += __shfl_down(p, 16);
    p += __shfl_down(p, 8);
    p += __shfl_down(p, 4);
    p += __shfl_down(p, 2);
    p += __shfl_down(p, 1);
    if (lane == 0) out[s] = p + pol_b[0];    // fp32 store — output is float32
}

extern "C" void kernel_launch(void* const* d_in, const int* in_sizes, int n_in,
                              void* d_out, int out_size, void* d_ws, size_t ws_size,
                              hipStream_t stream) {
    const float* x       = (const float*)d_in[0];
    const int*   seg_ids = (const int*)d_in[1];
    // d_in[2], d_in[3] = B, D scalars (constants here)
    const float* tfc0_w = (const float*)d_in[4];
    const float* tfc0_b = (const float*)d_in[5];
    const float* tfc1_w = (const float*)d_in[6];
    const float* tfc1_b = (const float*)d_in[7];
    const float* fwd0_w = (const float*)d_in[8];
    const float* fwd0_b = (const float*)d_in[9];
    const float* fwd1_w = (const float*)d_in[10];
    const float* fwd1_b = (const float*)d_in[11];
    const float* com0_w = (const float*)d_in[12];
    const float* com0_b = (const float*)d_in[13];
    const float* com1_w = (const float*)d_in[14];
    const float* com1_b = (const float*)d_in[15];
    const float* bwd0_w = (const float*)d_in[16];
    const float* bwd0_b = (const float*)d_in[17];
    const float* bwd1_w = (const float*)d_in[18];
    const float* bwd1_b = (const float*)d_in[19];
    const float* rl0_w  = (const float*)d_in[20];
    const float* rl0_b  = (const float*)d_in[21];
    const float* rl1_w  = (const float*)d_in[22];
    const float* rl1_b  = (const float*)d_in[23];
    const float* cost0_w = (const float*)d_in[24];
    const float* cost0_b = (const float*)d_in[25];
    const float* cost1_w = (const float*)d_in[26];
    const float* cost1_b = (const float*)d_in[27];
    const float* pol_w   = (const float*)d_in[28];
    const float* pol_b   = (const float*)d_in[29];

    char* ws = (char*)d_ws;
    const size_t seg_bytes = (size_t)S_SEG * 32 * sizeof(float);   // 2 MB each
    float* seg  = (float*)ws;
    float* rseg = (float*)(ws + seg_bytes);
    u16* w0T = (u16*)(ws + 2 * seg_bytes);
    u16* w1T = w0T + 128 * 64;
    u16* r0T = w1T + 32 * 128;
    u16* r1T = r0T + 128 * 64;

    // 1) zero segment accumulators (ws is re-poisoned before every launch)
    int n4 = (int)(2 * seg_bytes / 16);
    zero_ws_kernel<<<(n4 + 255) / 256, 256, 0, stream>>>(seg, n4);
    // 2) transpose + bf16-convert weights into ws
    transpose_weights<<<96, 256, 0, stream>>>(tfc0_w, tfc1_w, rl0_w, rl1_w,
                                              w0T, w1T, r0T, r1T);
    // 3) main fused MLP + segment-sum
    main_mlp_seg<<<(N_ROWS + ROWS_PB - 1) / ROWS_PB, 256, 0, stream>>>(
        x, seg_ids, w0T, tfc0_b, w1T, tfc1_b, r0T, rl0_b, r1T, rl1_b, seg, rseg);
    // 4) per-segment heads + cost MLP + policy
    heads_kernel<<<S_SEG / 4, 256, 0, stream>>>(
        seg, rseg,
        fwd0_w, fwd0_b, fwd1_w, fwd1_b,
        com0_w, com0_b, com1_w, com1_b,
        bwd0_w, bwd0_b, bwd1_w, bwd1_b,
        cost0_w, cost0_b, cost1_w, cost1_b,
        pol_w, pol_b, (float*)d_out);
}

// Round 6
// 828.439 us; speedup vs baseline: 1.0052x; 1.0052x over previous
//
#include <hip/hip_runtime.h>

typedef unsigned short u16;
typedef __bf16  bf16x8 __attribute__((ext_vector_type(8)));
typedef float   f32x4  __attribute__((ext_vector_type(4)));

#define N_ROWS 1500000
#define S_SEG  16384
#define ROWS_PB 32          // 1.5M / 32 = 46875 exactly -> no tail handling

__device__ __forceinline__ u16 f2bf(float f) {
    unsigned int u = __float_as_uint(f);
    u += 0x7FFF + ((u >> 16) & 1);   // RNE
    return (u16)(u >> 16);
}

// ---------------- zero the fp32 segment accumulators ----------------
__global__ void zero_ws_kernel(float* p, int n4) {
    int i = blockIdx.x * 256 + threadIdx.x;
    if (i < n4) reinterpret_cast<float4*>(p)[i] = make_float4(0.f, 0.f, 0.f, 0.f);
}

// ------- transpose + fp32->bf16 convert the 4 big-GEMM weight matrices -------
__global__ void transpose_weights(const float* __restrict__ w0, const float* __restrict__ w1,
                                  const float* __restrict__ r0, const float* __restrict__ r1,
                                  u16* __restrict__ w0T, u16* __restrict__ w1T,
                                  u16* __restrict__ r0T, u16* __restrict__ r1T) {
    int idx = blockIdx.x * 256 + threadIdx.x;     // 0 .. 24576
    if (idx < 8192) {
        int o = idx >> 6, k = idx & 63;
        w0T[o * 64 + k] = f2bf(w0[k * 128 + o]);
    } else if (idx < 12288) {
        int t = idx - 8192; int o = t >> 7, k = t & 127;
        w1T[o * 128 + k] = f2bf(w1[k * 32 + o]);
    } else if (idx < 20480) {
        int t = idx - 12288; int o = t >> 6, k = t & 63;
        r0T[o * 64 + k] = f2bf(r0[k * 128 + o]);
    } else if (idx < 24576) {
        int t = idx - 20480; int o = t >> 7, k = t & 127;
        r1T[o * 128 + k] = f2bf(r1[k * 32 + o]);
    }
}

// ---------------- main: per-row 2-layer MLP x2 branches + segment atomics ----------------
// 32 rows/block, 4 waves, MFMA 16x16x32 bf16.
// A-frag: A[m=lane&15][k=(lane>>4)*8+j];  B-frag: B[k=(lane>>4)*8+j][n=lane&15]
// C/D   : col=lane&15, row=(lane>>4)*4+reg
// LDS: xs 4608 + h1s 8704 + h2s 8448 + ids 128 = 21888 B -> 7 blocks/CU (87% occ).
#define XS_LD 72
#define H1_LD 136
#define H2B_LD 66   // 64 cols (tfc 0-31 | rl 32-63) + 2 pad, fp32

__global__ __launch_bounds__(256) void main_mlp_seg(
    const float* __restrict__ x, const int* __restrict__ seg_ids,
    const u16* __restrict__ w0T, const float* __restrict__ b0a,
    const u16* __restrict__ w1T, const float* __restrict__ b1a,
    const u16* __restrict__ r0T, const float* __restrict__ rb0,
    const u16* __restrict__ r1T, const float* __restrict__ rb1,
    float* __restrict__ seg_out, float* __restrict__ rseg_out)
{
    __shared__ u16   xs [ROWS_PB * XS_LD];
    __shared__ u16   h1s[ROWS_PB * H1_LD];
    __shared__ float h2s[ROWS_PB * H2B_LD];
    __shared__ int   s_ids[ROWS_PB];

    const int tid = threadIdx.x;
    const int i0  = blockIdx.x * ROWS_PB;

    if (tid < ROWS_PB) s_ids[tid] = seg_ids[i0 + tid];

    // stage x tile: 32 rows x 64 fp32 -> bf16 in LDS (coalesced float4, 2/thread)
    #pragma unroll
    for (int j = 0; j < 2; ++j) {
        int ch = tid + j * 256;          // 0..511
        int r = ch >> 4, c4 = ch & 15;   // 16 float4 per row
        float4 v = *reinterpret_cast<const float4*>(x + (size_t)(i0 + r) * 64 + c4 * 4);
        ushort4 pk;
        pk.x = f2bf(v.x); pk.y = f2bf(v.y); pk.z = f2bf(v.z); pk.w = f2bf(v.w);
        *reinterpret_cast<ushort4*>(&xs[r * XS_LD + c4 * 4]) = pk;
    }
    __syncthreads();

    const int wid = tid >> 6, lane = tid & 63;
    const int m = lane & 15, q = lane >> 4;

    #pragma unroll 1
    for (int br = 0; br < 2; ++br) {
        const u16*   W0 = br ? r0T : w0T;
        const float* B0 = br ? rb0 : b0a;
        const u16*   W1 = br ? r1T : w1T;
        const float* B1 = br ? rb1 : b1a;

        // ---- GEMM1: [32,64] @ [64,128] -> relu -> h1s (bf16) ----
        // wave `wid` owns col-tiles {2*wid, 2*wid+1}, loops 2 row-tiles
        bf16x8 bf[2][2];
        float bias0v[2];
        #pragma unroll
        for (int ct = 0; ct < 2; ++ct) {
            int n0 = (2 * wid + ct) * 16;
            #pragma unroll
            for (int ks = 0; ks < 2; ++ks)
                bf[ct][ks] = *reinterpret_cast<const bf16x8*>(W0 + (n0 + m) * 64 + ks * 32 + q * 8);
            bias0v[ct] = B0[n0 + m];
        }
        #pragma unroll
        for (int rt = 0; rt < 2; ++rt) {
            bf16x8 a0 = *reinterpret_cast<const bf16x8*>(&xs[(rt * 16 + m) * XS_LD + 0  + q * 8]);
            bf16x8 a1 = *reinterpret_cast<const bf16x8*>(&xs[(rt * 16 + m) * XS_LD + 32 + q * 8]);
            #pragma unroll
            for (int ct = 0; ct < 2; ++ct) {
                f32x4 acc = {0.f, 0.f, 0.f, 0.f};
                acc = __builtin_amdgcn_mfma_f32_16x16x32_bf16(a0, bf[ct][0], acc, 0, 0, 0);
                acc = __builtin_amdgcn_mfma_f32_16x16x32_bf16(a1, bf[ct][1], acc, 0, 0, 0);
                int colg = (2 * wid + ct) * 16 + m;
                #pragma unroll
                for (int i = 0; i < 4; ++i) {
                    float v = fmaxf(acc[i] + bias0v[ct], 0.f);
                    h1s[(rt * 16 + q * 4 + i) * H1_LD + colg] = f2bf(v);
                }
            }
        }
        __syncthreads();

        // ---- GEMM2: [32,128] @ [128,32] -> relu -> h2s[., br*32+c] (fp32) ----
        // 4 output tiles (2 rt x 2 ct); wave w owns (rt=w&1, ct=w>>1)
        {
            int rt = wid & 1, ct = wid >> 1;
            float bias1v = B1[ct * 16 + m];
            bf16x8 a[4], bg[4];
            #pragma unroll
            for (int ks = 0; ks < 4; ++ks) {
                bg[ks] = *reinterpret_cast<const bf16x8*>(W1 + (ct * 16 + m) * 128 + ks * 32 + q * 8);
                a[ks]  = *reinterpret_cast<const bf16x8*>(&h1s[(rt * 16 + m) * H1_LD + ks * 32 + q * 8]);
            }
            f32x4 acc = {0.f, 0.f, 0.f, 0.f};
            #pragma unroll
            for (int ks = 0; ks < 4; ++ks)
                acc = __builtin_amdgcn_mfma_f32_16x16x32_bf16(a[ks], bg[ks], acc, 0, 0, 0);
            int colg = br * 32 + ct * 16 + m;
            #pragma unroll
            for (int i = 0; i < 4; ++i) {
                float v = fmaxf(acc[i] + bias1v, 0.f);
                h2s[(rt * 16 + q * 4 + i) * H2B_LD + colg] = v;
            }
        }
        __syncthreads();   // h2s half ready; also protects h1s for next branch
    }

    // ---- sorted-run segment accumulate, both branches at once ----
    // thread = (c in [0,64), 8-row group g in [0,4)); cols 0-31 tfc, 32-63 rl
    {
        int c = tid & 63, g = tid >> 6;
        float* sp  = (c < 32) ? seg_out : rseg_out;
        int    col = c & 31;
        int cur = -1; float acc = 0.f;
        #pragma unroll
        for (int r = 0; r < 8; ++r) {
            int rr = g * 8 + r;
            int id = s_ids[rr];
            if (id != cur) {
                if (cur >= 0) atomicAdd(&sp[cur * 32 + col], acc);
                cur = id; acc = 0.f;
            }
            acc += h2s[rr * H2B_LD + c];
        }
        if (cur >= 0) atomicAdd(&sp[cur * 32 + col], acc);
    }
}

// ---------------- per-segment heads + cost MLP + policy (fp32 in, fp32 out) ----------------
__global__ __launch_bounds__(256) void heads_kernel(
    const float* __restrict__ seg, const float* __restrict__ rseg,
    const float* __restrict__ fwd0_w, const float* __restrict__ fwd0_b,
    const float* __restrict__ fwd1_w, const float* __restrict__ fwd1_b,
    const float* __restrict__ com0_w, const float* __restrict__ com0_b,
    const float* __restrict__ com1_w, const float* __restrict__ com1_b,
    const float* __restrict__ bwd0_w, const float* __restrict__ bwd0_b,
    const float* __restrict__ bwd1_w, const float* __restrict__ bwd1_b,
    const float* __restrict__ cost0_w, const float* __restrict__ cost0_b,
    const float* __restrict__ cost1_w, const float* __restrict__ cost1_b,
    const float* __restrict__ pol_w, const float* __restrict__ pol_b,
    float* __restrict__ out)
{
    __shared__ float s_seg[4][32];
    __shared__ float s_rseg[4][32];
    __shared__ float s_c0[4][64];
    const int tid = threadIdx.x, wid = tid >> 6, lane = tid & 63;
    const int s = blockIdx.x * 4 + wid;

    if (lane < 32) {
        s_seg[wid][lane]  = seg[s * 32 + lane];
        s_rseg[wid][lane] = rseg[s * 32 + lane];
    }
    __syncthreads();

    const float* w0s[3] = {fwd0_w, com0_w, bwd0_w};
    const float* b0s[3] = {fwd0_b, com0_b, bwd0_b};
    const float* w1s[3] = {fwd1_w, com1_w, bwd1_w};
    const float* b1s[3] = {fwd1_b, com1_b, bwd1_b};
    float costs[3];
    #pragma unroll
    for (int hh = 0; hh < 3; ++hh) {
        float t = 0.f;
        #pragma unroll
        for (int k = 0; k < 32; ++k)
            t = fmaf(s_seg[wid][k], w0s[hh][k * 64 + lane], t);
        t = fmaxf(t + b0s[hh][lane], 0.f);
        float red = t * w1s[hh][lane];
        red += __shfl_down(red, 32);
        red += __shfl_down(red, 16);
        red += __shfl_down(red, 8);
        red += __shfl_down(red, 4);
        red += __shfl_down(red, 2);
        red += __shfl_down(red, 1);
        costs[hh] = __shfl(red, 0) + b1s[hh][0];
    }

    float c0 = costs[0] * cost0_w[lane] +
               costs[1] * cost0_w[64 + lane] +
               costs[2] * cost0_w[128 + lane] + cost0_b[lane];
    c0 = fmaxf(c0, 0.f);
    s_c0[wid][lane] = c0;
    __syncthreads();

    int kk = lane & 31;
    float c1 = 0.f;
    #pragma unroll 8
    for (int j = 0; j < 64; ++j)
        c1 = fmaf(s_c0[wid][j], cost1_w[j * 32 + kk], c1);
    c1 = fmaxf(c1 + cost1_b[kk], 0.f);

    float p = 0.f;
    if (lane < 32)
        p = s_rseg[wid][lane] * pol_w[lane] + c1 * pol_w[32 + lane];
    p += __shfl_down(p, 32);
    p += __shfl_down(p, 16);
    p += __shfl_down(p, 8);
    p += __shfl_down(p, 4);
    p += __shfl_down(p, 2);
    p += __shfl_down(p, 1);
    if (lane == 0) out[s] = p + pol_b[0];    // fp32 output
}

extern "C" void kernel_launch(void* const* d_in, const int* in_sizes, int n_in,
                              void* d_out, int out_size, void* d_ws, size_t ws_size,
                              hipStream_t stream) {
    const float* x       = (const float*)d_in[0];
    const int*   seg_ids = (const int*)d_in[1];
    const float* tfc0_w = (const float*)d_in[4];
    const float* tfc0_b = (const float*)d_in[5];
    const float* tfc1_w = (const float*)d_in[6];
    const float* tfc1_b = (const float*)d_in[7];
    const float* fwd0_w = (const float*)d_in[8];
    const float* fwd0_b = (const float*)d_in[9];
    const float* fwd1_w = (const float*)d_in[10];
    const float* fwd1_b = (const float*)d_in[11];
    const float* com0_w = (const float*)d_in[12];
    const float* com0_b = (const float*)d_in[13];
    const float* com1_w = (const float*)d_in[14];
    const float* com1_b = (const float*)d_in[15];
    const float* bwd0_w = (const float*)d_in[16];
    const float* bwd0_b = (const float*)d_in[17];
    const float* bwd1_w = (const float*)d_in[18];
    const float* bwd1_b = (const float*)d_in[19];
    const float* rl0_w  = (const float*)d_in[20];
    const float* rl0_b  = (const float*)d_in[21];
    const float* rl1_w  = (const float*)d_in[22];
    const float* rl1_b  = (const float*)d_in[23];
    const float* cost0_w = (const float*)d_in[24];
    const float* cost0_b = (const float*)d_in[25];
    const float* cost1_w = (const float*)d_in[26];
    const float* cost1_b = (const float*)d_in[27];
    const float* pol_w   = (const float*)d_in[28];
    const float* pol_b   = (const float*)d_in[29];

    char* ws = (char*)d_ws;
    const size_t seg_bytes = (size_t)S_SEG * 32 * sizeof(float);   // 2 MB each
    float* seg  = (float*)ws;
    float* rseg = (float*)(ws + seg_bytes);
    u16* w0T = (u16*)(ws + 2 * seg_bytes);
    u16* w1T = w0T + 128 * 64;
    u16* r0T = w1T + 32 * 128;
    u16* r1T = r0T + 128 * 64;

    int n4 = (int)(2 * seg_bytes / 16);
    zero_ws_kernel<<<(n4 + 255) / 256, 256, 0, stream>>>(seg, n4);
    transpose_weights<<<96, 256, 0, stream>>>(tfc0_w, tfc1_w, rl0_w, rl1_w,
                                              w0T, w1T, r0T, r1T);
    main_mlp_seg<<<N_ROWS / ROWS_PB, 256, 0, stream>>>(
        x, seg_ids, w0T, tfc0_b, w1T, tfc1_b, r0T, rl0_b, r1T, rl1_b, seg, rseg);
    heads_kernel<<<S_SEG / 4, 256, 0, stream>>>(
        seg, rseg,
        fwd0_w, fwd0_b, fwd1_w, fwd1_b,
        com0_w, com0_b, com1_w, com1_b,
        bwd0_w, bwd0_b, bwd1_w, bwd1_b,
        cost0_w, cost0_b, cost1_w, cost1_b,
        pol_w, pol_b, (float*)d_out);
}